// Round 3
// baseline (623.827 us; speedup 1.0000x reference)
//
#include <hip/hip_runtime.h>
#include <math.h>

#define N_NODES 32768
#define F 128
#define KD 64

typedef short  s8v  __attribute__((ext_vector_type(8)));   // 8 x bf16 (bit pattern)
typedef float  f4v  __attribute__((ext_vector_type(4)));   // MFMA accumulator
typedef unsigned short u16;

__device__ __forceinline__ float ssp(float a) {
    return fmaxf(a, 0.0f) + log1pf(expf(-fabsf(a))) - 0.69314718055994531f;
}
__device__ __forceinline__ u16 f2b(float f) {               // fp32 -> bf16 RNE
    unsigned int u = __builtin_bit_cast(unsigned int, f);
    u += 0x7fffu + ((u >> 16) & 1u);
    return (u16)(u >> 16);
}
__device__ __forceinline__ float b2f(u16 h) {
    unsigned int u = ((unsigned int)h) << 16;
    return __builtin_bit_cast(float, u);
}

// Wave-level LDS fence: orders same-wave cross-lane LDS write->read without
// __syncthreads. lgkmcnt(0) drains DS ops; wave_barrier + sched_barrier stop
// the scheduler hoisting dependent ops across it (guide rule #18).
__device__ __forceinline__ void wfence() {
    asm volatile("s_waitcnt lgkmcnt(0)" ::: "memory");
    __builtin_amdgcn_wave_barrier();
    __builtin_amdgcn_sched_barrier(0);
}

// ---------------------------------------------------------------------------
// Per-wave MFMA GEMM: 16 rows (A in wave-private LDS [16][136] bf16) x 128
// cols x K=128. B-frags direct from global bf16 weights (L1-resident).
// C/D: col=lane&15, row=(lane>>4)*4+reg.
// ---------------------------------------------------------------------------
__device__ __forceinline__ void gemm16(const u16* S, const u16* Wg,
                                       int m, int q, f4v acc[8])
{
    #pragma unroll
    for (int ct = 0; ct < 8; ++ct) acc[ct] = (f4v){0.f, 0.f, 0.f, 0.f};
    #pragma unroll
    for (int ks = 0; ks < 4; ++ks) {
        s8v a = *(const s8v*)&S[m * 136 + ks * 32 + q * 8];
        #pragma unroll
        for (int ct = 0; ct < 8; ++ct) {
            s8v b = *(const s8v*)&Wg[(ct * 16 + m) * 128 + ks * 32 + q * 8];
            acc[ct] = __builtin_amdgcn_mfma_f32_16x16x32_bf16(a, b, acc[ct], 0, 0, 0);
        }
    }
}

// Same, A-frags already in registers (a[ks] holds A[m][ks*32+q*8 .. +7]).
__device__ __forceinline__ void gemm16_regA(const s8v a[4], const u16* Wg,
                                            int m, int q, f4v acc[8])
{
    #pragma unroll
    for (int ct = 0; ct < 8; ++ct) acc[ct] = (f4v){0.f, 0.f, 0.f, 0.f};
    #pragma unroll
    for (int ks = 0; ks < 4; ++ks) {
        #pragma unroll
        for (int ct = 0; ct < 8; ++ct) {
            s8v b = *(const s8v*)&Wg[(ct * 16 + m) * 128 + ks * 32 + q * 8];
            acc[ct] = __builtin_amdgcn_mfma_f32_16x16x32_bf16(a[ks], b, acc[ct], 0, 0, 0);
        }
    }
}

// C-layout -> A-layout restage into wave-private LDS [16][136].
__device__ __forceinline__ void writeA16(u16* S, int q, int m, const float v[8][4])
{
    #pragma unroll
    for (int ct = 0; ct < 8; ++ct) {
        int c = ct * 16 + m;
        #pragma unroll
        for (int reg = 0; reg < 4; ++reg)
            S[(q * 4 + reg) * 136 + c] = f2b(v[ct][reg]);
    }
}

// ---------------------------------------------------------------------------
// prep: fp32 -> bf16 for weights + k2f.
// ---------------------------------------------------------------------------
__global__ __launch_bounds__(256)
void prep_kernel(const float* __restrict__ wi, const float* __restrict__ wj,
                 const float* __restrict__ rw1, const float* __restrict__ rw2,
                 const float* __restrict__ wd, const float* __restrict__ k2f,
                 u16* __restrict__ WB, u16* __restrict__ K2FB)
{
    int b = blockIdx.x, t = threadIdx.x;
    const float* src; u16* dst; int off;
    if (b < 112) {
        int seg = b >> 4; off = (b & 15) * 1024 + t * 4;
        const float* srcs[7] = {wi, wj, rw1, rw2, rw1 + 16384, rw2 + 16384, wd};
        src = srcs[seg]; dst = WB + seg * 16384;
    } else {
        off = (b - 112) * 1024 + t * 4;
        src = k2f; dst = K2FB;
    }
    float4 v = *(const float4*)(src + off);
    ushort4 h; h.x = f2b(v.x); h.y = f2b(v.y); h.z = f2b(v.z); h.w = f2b(v.w);
    *(ushort4*)(dst + off) = h;
}

// ---------------------------------------------------------------------------
// in: wave-autonomous, NO __syncthreads. Each wave owns 16 rows; A-frags are
// loaded per-lane directly from global (MFMA A-layout = per-lane row slices,
// 128B-contiguous per (row,ks) across q-lanes), ssp applied in-register, and
// BOTH GEMMs (wi, wj) share the staged A. xv restaged through wave-private
// LDS for coalesced bf16 stores.
// ---------------------------------------------------------------------------
__global__ __launch_bounds__(256, 2)
void in_kernel(const float* __restrict__ x, const u16* __restrict__ WB,
               const float* __restrict__ bi, const float* __restrict__ bj,
               float* __restrict__ xi_out, u16* __restrict__ xv_out)
{
    __shared__ u16 st[4][16 * 136];               // per-wave restage (17408 B)
    const int t = threadIdx.x, wid = t >> 6, lane = t & 63;
    const int row0 = (blockIdx.x * 4 + wid) * 16;
    const int m = lane & 15, q = lane >> 4;

    // A-frags: lane(m,q) holds A[row0+m][ks*32+q*8 .. +7] = bf16(ssp(x))
    s8v a[4];
    const float* xr = x + (size_t)(row0 + m) * F + q * 8;
    #pragma unroll
    for (int ks = 0; ks < 4; ++ks) {
        float4 v0 = *(const float4*)(xr + ks * 32);
        float4 v1 = *(const float4*)(xr + ks * 32 + 4);
        a[ks][0] = (short)f2b(ssp(v0.x)); a[ks][1] = (short)f2b(ssp(v0.y));
        a[ks][2] = (short)f2b(ssp(v0.z)); a[ks][3] = (short)f2b(ssp(v0.w));
        a[ks][4] = (short)f2b(ssp(v1.x)); a[ks][5] = (short)f2b(ssp(v1.y));
        a[ks][6] = (short)f2b(ssp(v1.z)); a[ks][7] = (short)f2b(ssp(v1.w));
    }

    f4v acc[8];
    // ---- GEMM wi -> xi (fp32, 64B-segment stores)
    gemm16_regA(a, WB + 0 * 16384, m, q, acc);
    #pragma unroll
    for (int ct = 0; ct < 8; ++ct) {
        int c = ct * 16 + m; float bv = bi[c];
        #pragma unroll
        for (int reg = 0; reg < 4; ++reg)
            xi_out[(size_t)(row0 + q * 4 + reg) * F + c] = acc[ct][reg] + bv;
    }
    // ---- GEMM wj -> xv (bf16, coalesced via wave-private LDS restage)
    gemm16_regA(a, WB + 1 * 16384, m, q, acc);
    u16* S = st[wid];
    #pragma unroll
    for (int ct = 0; ct < 8; ++ct) {
        int c = ct * 16 + m; float bv = bj[c];
        #pragma unroll
        for (int reg = 0; reg < 4; ++reg)
            S[(q * 4 + reg) * 136 + c] = f2b(acc[ct][reg] + bv);
    }
    wfence();
    u16* dst = xv_out + (size_t)row0 * F;
    #pragma unroll
    for (int i = 0; i < 8; ++i) {                  // 16 rows x 32 ushort4 chunks
        int idx = i * 64 + lane, r = idx >> 5, seg = idx & 31;
        *(ushort4*)&dst[r * F + seg * 4] = *(const ushort4*)&S[r * 136 + seg * 4];
    }
}

// ---------------------------------------------------------------------------
// attn: wave-autonomous, NO __syncthreads. One wave = one node = 32 edges.
// All phases (gather, g-MFMA, multiply, logits, softmax, combine) run on
// wave-private LDS with wfence() ordering -> 16 independent pipelines/CU
// (4 blocks x 4 waves) instead of 4 barrier-locked blocks. Per-block phase
// chains were the measured bottleneck (all counters idle; per-block latency
// grew when residency rose at (256,5)).
// ---------------------------------------------------------------------------
__global__ __launch_bounds__(256, 4)
void attn_kernel(const float* __restrict__ xi_in, const u16* __restrict__ xvb,
                 const float* __restrict__ rbf, const int* __restrict__ idx_j,
                 const u16* __restrict__ k2fb, float* __restrict__ m_out)
{
    __shared__ u16   xj_s[4][32 * 136];   // 34816 B
    __shared__ float xi_s[4][128];        //  2048 B
    __shared__ float att_s[4][32];        //   512 B  -> 37376 B total, 4 blk/CU

    const int t = threadIdx.x, wid = t >> 6, lane = t & 63;
    const int node = blockIdx.x * 4 + wid;
    const size_t e0 = (size_t)node * 32;
    u16*   xj  = xj_s[wid];
    float* xi  = xi_s[wid];
    float* att = att_s[wid];

    // ---- gather xv[idx_j] to registers: lane (el=lane>>1, fh=lane&1) owns
    // edge el, f-half fh (64 f = 8 x s8v). In flight across the g-MFMA.
    const int el = lane >> 1, fh = lane & 1;
    const int jj = idx_j[e0 + el];
    const u16* xvp = xvb + (size_t)jj * F + fh * 64;
    s8v xv_r[8];
    #pragma unroll
    for (int i = 0; i < 8; ++i) xv_r[i] = *(const s8v*)(xvp + i * 8);

    // ---- xi -> wave LDS (float2 per lane)
    *(float2*)(xi + lane * 2) = *(const float2*)(xi_in + (size_t)node * F + lane * 2);

    // ---- g-GEMM: 32 edges x 128 cols, K=64, two 16-edge halves (acc reuse)
    const int m = lane & 15, q = lane >> 4;
    #pragma unroll
    for (int em = 0; em < 2; ++em) {
        f4v acc[8];
        #pragma unroll
        for (int ct = 0; ct < 8; ++ct) acc[ct] = (f4v){0.f, 0.f, 0.f, 0.f};
        const float* arow = rbf + (e0 + em * 16 + m) * KD;
        #pragma unroll
        for (int ks = 0; ks < 2; ++ks) {
            float4 a0 = *(const float4*)(arow + ks * 32 + q * 8);
            float4 a1 = *(const float4*)(arow + ks * 32 + q * 8 + 4);
            s8v a;
            a[0] = (short)f2b(a0.x); a[1] = (short)f2b(a0.y);
            a[2] = (short)f2b(a0.z); a[3] = (short)f2b(a0.w);
            a[4] = (short)f2b(a1.x); a[5] = (short)f2b(a1.y);
            a[6] = (short)f2b(a1.z); a[7] = (short)f2b(a1.w);
            #pragma unroll
            for (int ct = 0; ct < 8; ++ct) {
                s8v b = *(const s8v*)&k2fb[(ct * 16 + m) * KD + ks * 32 + q * 8];
                acc[ct] = __builtin_amdgcn_mfma_f32_16x16x32_bf16(a, b, acc[ct], 0, 0, 0);
            }
        }
        #pragma unroll
        for (int ct = 0; ct < 8; ++ct) {
            int c = ct * 16 + m;
            #pragma unroll
            for (int reg = 0; reg < 4; ++reg)
                xj[(em * 16 + q * 4 + reg) * 136 + c] = f2b(acc[ct][reg]);
        }
    }
    wfence();

    // ---- xj *= xv (registers): lane (el, fh): 8 x b128 RMW over 64 f
    #pragma unroll
    for (int i = 0; i < 8; ++i) {
        u16* p = &xj[el * 136 + fh * 64 + i * 8];
        s8v g8 = *(const s8v*)p, r;
        #pragma unroll
        for (int k = 0; k < 8; ++k)
            r[k] = (short)f2b(b2f((u16)g8[k]) * b2f((u16)xv_r[i][k]));
        *(s8v*)p = r;
    }
    wfence();

    // ---- logits (reshape-faithful): lane (fh2=lane>>5, mm=lane&31)
    // s[mm] = sum_f xi[f] * xj[f>>2][(f&3)*32+mm], f-halves combined by shfl.
    const int fh2 = lane >> 5, mm = lane & 31;
    float s = 0.f;
    #pragma unroll
    for (int fo = 0; fo < 64; ++fo) {
        int f = fh2 * 64 + fo;
        s = fmaf(xi[f], b2f(xj[(f >> 2) * 136 + (f & 3) * 32 + mm]), s);
    }
    s += __shfl_xor(s, 32);
    float mx = s;
    #pragma unroll
    for (int o = 16; o; o >>= 1) mx = fmaxf(mx, __shfl_xor(mx, o));
    float ex = expf(s - mx);
    float sum = ex;
    #pragma unroll
    for (int o = 16; o; o >>= 1) sum += __shfl_xor(sum, o);
    // both wave halves hold identical ex/sum; same-value same-address store
    att[mm] = ex / sum;
    wfence();

    // ---- combine: lane owns f = 2*lane, 2*lane+1 (u32 LDS reads, float2 out)
    float v0 = xi[lane * 2], v1 = xi[lane * 2 + 1];
    #pragma unroll
    for (int j = 0; j < 32; ++j) {
        float av = att[j];
        unsigned int pr = *(const unsigned int*)&xj[j * 136 + lane * 2];
        v0 = fmaf(av, b2f((u16)(pr & 0xffffu)), v0);
        v1 = fmaf(av, b2f((u16)(pr >> 16)), v1);
    }
    *(float2*)(m_out + (size_t)node * F + lane * 2) = make_float2(v0, v1);
}

// ---------------------------------------------------------------------------
// tail: wave-autonomous, NO __syncthreads. Each wave owns 16 rows, chains the
// 5 GEMMs through its private LDS tile (C-layout -> A-layout restage between
// GEMMs), wfence-ordered.
// ---------------------------------------------------------------------------
__global__ __launch_bounds__(256, 2)
void tail_kernel(const float* __restrict__ m_in, const float* __restrict__ x,
                 const float* __restrict__ u, const u16* __restrict__ WB,
                 const float* __restrict__ rb1, const float* __restrict__ rb2,
                 const float* __restrict__ bd, float* __restrict__ out)
{
    __shared__ u16 st[4][16 * 136];
    const int t = threadIdx.x, wid = t >> 6, lane = t & 63;
    const int row0 = (blockIdx.x * 4 + wid) * 16;
    const int m = lane & 15, q = lane >> 4;
    const int rbase = row0 + q * 4;
    u16* S = st[wid];

    float cur[8][4], tmp[8][4];
    #pragma unroll
    for (int ct = 0; ct < 8; ++ct) {
        int c = ct * 16 + m;
        #pragma unroll
        for (int reg = 0; reg < 4; ++reg)
            cur[ct][reg] = m_in[(size_t)(rbase + reg) * F + c];
    }

    f4v acc[8];
    #pragma unroll 1
    for (int r = 0; r < 2; ++r) {
        #pragma unroll
        for (int ct = 0; ct < 8; ++ct)
            #pragma unroll
            for (int reg = 0; reg < 4; ++reg) tmp[ct][reg] = ssp(cur[ct][reg]);
        writeA16(S, q, m, tmp);
        wfence();
        gemm16(S, WB + (2 + 2 * r) * 16384, m, q, acc);     // rw1_r
        wfence();                                           // reads done before rewrite
        #pragma unroll
        for (int ct = 0; ct < 8; ++ct) {
            float bv = rb1[r * F + ct * 16 + m];
            #pragma unroll
            for (int reg = 0; reg < 4; ++reg) tmp[ct][reg] = acc[ct][reg] + bv;
        }
        writeA16(S, q, m, tmp);
        wfence();
        gemm16(S, WB + (3 + 2 * r) * 16384, m, q, acc);     // rw2_r
        #pragma unroll
        for (int ct = 0; ct < 8; ++ct) {
            float bv = rb2[r * F + ct * 16 + m];
            #pragma unroll
            for (int reg = 0; reg < 4; ++reg) cur[ct][reg] += acc[ct][reg] + bv;
        }
        wfence();                                           // reads done before rewrite
    }

    #pragma unroll
    for (int ct = 0; ct < 8; ++ct)
        #pragma unroll
        for (int reg = 0; reg < 4; ++reg) tmp[ct][reg] = ssp(cur[ct][reg]);
    writeA16(S, q, m, tmp);
    wfence();
    gemm16(S, WB + 6 * 16384, m, q, acc);                   // wd
    #pragma unroll
    for (int ct = 0; ct < 8; ++ct) {
        int c = ct * 16 + m;
        float uv = u[c], bv = bd[c];
        #pragma unroll
        for (int reg = 0; reg < 4; ++reg) {
            size_t r = (size_t)(rbase + reg) * F + c;
            out[r] = fmaf(uv, x[r], acc[ct][reg] + bv);
        }
    }
}

// ---------------------------------------------------------------------------
extern "C" void kernel_launch(void* const* d_in, const int* in_sizes, int n_in,
                              void* d_out, int out_size, void* d_ws, size_t ws_size,
                              hipStream_t stream)
{
    const float* x     = (const float*)d_in[0];
    const float* rbf   = (const float*)d_in[1];
    const int*   idx_j = (const int*)d_in[3];   // idx_i (d_in[2]) unused by ref
    const float* k2f_w = (const float*)d_in[4];
    const float* wi    = (const float*)d_in[5];
    const float* bi    = (const float*)d_in[6];
    const float* wj    = (const float*)d_in[7];
    const float* bj    = (const float*)d_in[8];
    const float* rw1   = (const float*)d_in[9];
    const float* rb1   = (const float*)d_in[10];
    const float* rw2   = (const float*)d_in[11];
    const float* rb2   = (const float*)d_in[12];
    const float* wd    = (const float*)d_in[13];
    const float* bd    = (const float*)d_in[14];
    const float* u     = (const float*)d_in[15];
    float* out = (float*)d_out;

    const size_t NF = (size_t)N_NODES * F;
    float* B0   = (float*)d_ws;          // xi, then m (attn writes in place)
    u16*   XVB  = (u16*)(B0 + NF);       // xv bf16
    u16*   WB   = XVB + NF;              // 7 x [128][128] bf16 weights
    u16*   K2FB = WB + 7 * 16384;        // [128][64] bf16

    hipLaunchKernelGGL(prep_kernel, dim3(120), dim3(256), 0, stream,
                       wi, wj, rw1, rw2, wd, k2f_w, WB, K2FB);

    hipLaunchKernelGGL(in_kernel, dim3(N_NODES / 64), dim3(256), 0, stream,
                       x, WB, bi, bj, B0, XVB);

    hipLaunchKernelGGL(attn_kernel, dim3(N_NODES / 4), dim3(256), 0, stream,
                       B0, XVB, rbf, idx_j, K2FB, B0);

    hipLaunchKernelGGL(tail_kernel, dim3(N_NODES / 64), dim3(256), 0, stream,
                       B0, x, u, WB, rb1, rb2, bd, out);
}